// Round 6
// baseline (398.368 us; speedup 1.0000x reference)
//
#include <hip/hip_runtime.h>
#include <math.h>

static inline size_t align256(size_t x) { return (x + 255) & ~size_t(255); }

// ============ CSR construction ============

// 8-replica count: replica = blockIdx%8 ~ XCD id (round-robin dispatch), so the
// atomic lines stay in one XCD's L2. rank = slot within (replica, dst).
__global__ __launch_bounds__(256) void csr_count_rank8(const int* __restrict__ dst,
                                                       int* __restrict__ counts8,
                                                       int* __restrict__ rank, int E, int BN) {
    int e = blockIdx.x * blockDim.x + threadIdx.x;
    if (e >= E) return;
    int copy = blockIdx.x & 7;
    rank[e] = atomicAdd(&counts8[copy * BN + dst[e]], 1);
}

// per node: exclusive prefix over the 8 replicas (stored back in counts8),
// total degree -> totals
__global__ __launch_bounds__(256) void merge_counts(int* __restrict__ counts8,
                                                    int* __restrict__ totals, int BN) {
    int i = blockIdx.x * blockDim.x + threadIdx.x;
    if (i >= BN) return;
    int pre = 0;
#pragma unroll
    for (int c = 0; c < 8; ++c) {
        int v = counts8[c * BN + i];
        counts8[c * BN + i] = pre;
        pre += v;
    }
    totals[i] = pre;
}

__global__ __launch_bounds__(256) void block_reduce(const int* __restrict__ counts,
                                                    int* __restrict__ bsum, int BN) {
    __shared__ int red[256];
    int base = blockIdx.x * 1024;
    int s = 0;
    for (int k = threadIdx.x; k < 1024; k += 256) {
        int idx = base + k;
        s += (idx < BN) ? counts[idx] : 0;
    }
    red[threadIdx.x] = s;
    __syncthreads();
    for (int off = 128; off >= 1; off >>= 1) {
        if (threadIdx.x < off) red[threadIdx.x] += red[threadIdx.x + off];
        __syncthreads();
    }
    if (threadIdx.x == 0) bsum[blockIdx.x] = red[0];
}

__global__ __launch_bounds__(1024) void scan_small(const int* __restrict__ bsum,
                                                   int* __restrict__ bpre, int nb) {
    __shared__ int buf[1024];
    int tid = threadIdx.x;
    buf[tid] = (tid < nb) ? bsum[tid] : 0;
    __syncthreads();
    for (int off = 1; off < 1024; off <<= 1) {
        int v = (tid >= off) ? buf[tid - off] : 0;
        __syncthreads();
        buf[tid] += v;
        __syncthreads();
    }
    if (tid < nb) bpre[tid] = (tid == 0) ? 0 : buf[tid - 1];
}

__global__ __launch_bounds__(256) void block_scan(const int* __restrict__ counts,
                                                  const int* __restrict__ bpre,
                                                  int* __restrict__ offs, int BN) {
    __shared__ int tsum[256];
    int base = blockIdx.x * 1024;
    int tbase = base + threadIdx.x * 4;
    int c0 = 0, c1 = 0, c2 = 0, c3 = 0;
    if (tbase + 0 < BN) c0 = counts[tbase + 0];
    if (tbase + 1 < BN) c1 = counts[tbase + 1];
    if (tbase + 2 < BN) c2 = counts[tbase + 2];
    if (tbase + 3 < BN) c3 = counts[tbase + 3];
    int local = c0 + c1 + c2 + c3;
    tsum[threadIdx.x] = local;
    __syncthreads();
    for (int off = 1; off < 256; off <<= 1) {
        int v = (threadIdx.x >= off) ? tsum[threadIdx.x - off] : 0;
        __syncthreads();
        tsum[threadIdx.x] += v;
        __syncthreads();
    }
    int prefix = bpre[blockIdx.x] + tsum[threadIdx.x] - local;  // exclusive
    if (tbase + 0 < BN) offs[tbase + 0] = prefix;
    prefix += c0;
    if (tbase + 1 < BN) offs[tbase + 1] = prefix;
    prefix += c1;
    if (tbase + 2 < BN) offs[tbase + 2] = prefix;
    prefix += c2;
    if (tbase + 3 < BN) offs[tbase + 3] = prefix;
}

// fill with NO atomics: pos = offs[dst] + replica-prefix + rank
__global__ __launch_bounds__(256) void csr_fill3(const int* __restrict__ src,
                                                 const int* __restrict__ dst,
                                                 const int* __restrict__ rank,
                                                 const int* __restrict__ offs,
                                                 const int* __restrict__ counts8,
                                                 int* __restrict__ esrc, int E, int BN) {
    int e = blockIdx.x * blockDim.x + threadIdx.x;
    if (e >= E) return;
    int copy = blockIdx.x & 7;
    int d = dst[e];
    esrc[offs[d] + counts8[copy * BN + d] + rank[e]] = src[e];
}

// ============ layer 1 ============

__global__ __launch_bounds__(256) void gather16(const float4* __restrict__ h4,
                                                const int* __restrict__ offs,
                                                const int* __restrict__ cnts,
                                                const int* __restrict__ esrc,
                                                float4* __restrict__ out4, int BN) {
    int t = blockIdx.x * blockDim.x + threadIdx.x;
    int i = t >> 2, c = t & 3;
    if (i >= BN) return;
    float4 acc = h4[(size_t)i * 4 + c];
    int start = offs[i], deg = cnts[i];
    int j = 0;
    for (; j + 4 <= deg; j += 4) {
        int s0 = esrc[start + j], s1 = esrc[start + j + 1];
        int s2 = esrc[start + j + 2], s3 = esrc[start + j + 3];
        float4 v0 = h4[(size_t)s0 * 4 + c];
        float4 v1 = h4[(size_t)s1 * 4 + c];
        float4 v2 = h4[(size_t)s2 * 4 + c];
        float4 v3 = h4[(size_t)s3 * 4 + c];
        acc.x += (v0.x + v1.x) + (v2.x + v3.x);
        acc.y += (v0.y + v1.y) + (v2.y + v3.y);
        acc.z += (v0.z + v1.z) + (v2.z + v3.z);
        acc.w += (v0.w + v1.w) + (v2.w + v3.w);
    }
    for (; j < deg; ++j) {
        int s = esrc[start + j];
        float4 v = h4[(size_t)s * 4 + c];
        acc.x += v.x; acc.y += v.y; acc.z += v.z; acc.w += v.w;
    }
    out4[(size_t)i * 4 + c] = acc;
}

__global__ __launch_bounds__(256) void lin1_wave(const float* __restrict__ x,
                                                 const float* __restrict__ W1,
                                                 const float* __restrict__ b1,
                                                 float* __restrict__ y, int BN) {
    __shared__ float xb[4][16];
    int tid = threadIdx.x;
    int lane = tid & 63, wv = tid >> 6;
    int gw = (int)((blockIdx.x * blockDim.x + tid) >> 6);
    int nw = (int)((gridDim.x * blockDim.x) >> 6);
    float wcol[16];
#pragma unroll
    for (int k = 0; k < 16; ++k) wcol[k] = W1[k * 64 + lane];
    float breg = b1[lane];
    for (int i = gw; i < BN; i += nw) {
        float x0 = x[(size_t)i * 16 + (lane & 15)];
        if (lane < 16) xb[wv][lane] = x0;
        float acc = breg;
#pragma unroll
        for (int k4 = 0; k4 < 4; ++k4) {
            float4 xv = *(const float4*)&xb[wv][k4 * 4];
            acc = fmaf(xv.x, wcol[k4 * 4 + 0], acc);
            acc = fmaf(xv.y, wcol[k4 * 4 + 1], acc);
            acc = fmaf(xv.z, wcol[k4 * 4 + 2], acc);
            acc = fmaf(xv.w, wcol[k4 * 4 + 3], acc);
        }
        y[(size_t)i * 64 + lane] = fmaxf(acc, 0.f);
    }
}

// ============ fused layer 2: gather + lin2 + relu + project to (q, r) ============
__global__ __launch_bounds__(256, 4) void gather64_lin2_qr(const float* __restrict__ h1,
                                                           const int* __restrict__ offs,
                                                           const int* __restrict__ cnts,
                                                           const int* __restrict__ esrc,
                                                           const float* __restrict__ W2,
                                                           const float* __restrict__ b2,
                                                           const float* __restrict__ wlin,
                                                           float* __restrict__ q,
                                                           float* __restrict__ r, int BN) {
    __shared__ float xbuf[4][64];
    __shared__ int   ibuf[4][64];
    int tid = threadIdx.x;
    int lane = tid & 63, wv = tid >> 6;
    int gw = (int)((blockIdx.x * blockDim.x + tid) >> 6);
    int nw = (int)((gridDim.x * blockDim.x) >> 6);
    float wcol[64];
#pragma unroll
    for (int k = 0; k < 64; ++k) wcol[k] = W2[k * 64 + lane];
    float breg = b2[lane];
    float wlo = wlin[lane];
    float whi = wlin[64 + lane];
    const float* hl = h1 + lane;
    for (int i = gw; i < BN; i += nw) {
        float acc = hl[(size_t)i * 64];
        int start = offs[i], deg = cnts[i];
        for (int j0 = 0; j0 < deg; j0 += 64) {
            int m = min(64, deg - j0);
            if (lane < m) ibuf[wv][lane] = esrc[start + j0 + lane];
            int jj = 0;
            for (; jj + 8 <= m; jj += 8) {
                int4 ia = *(const int4*)&ibuf[wv][jj];
                int4 ib = *(const int4*)&ibuf[wv][jj + 4];
                float v0 = hl[(size_t)ia.x * 64];
                float v1 = hl[(size_t)ia.y * 64];
                float v2 = hl[(size_t)ia.z * 64];
                float v3 = hl[(size_t)ia.w * 64];
                float v4 = hl[(size_t)ib.x * 64];
                float v5 = hl[(size_t)ib.y * 64];
                float v6 = hl[(size_t)ib.z * 64];
                float v7 = hl[(size_t)ib.w * 64];
                acc += ((v0 + v1) + (v2 + v3)) + ((v4 + v5) + (v6 + v7));
            }
            for (; jj + 4 <= m; jj += 4) {
                int4 ia = *(const int4*)&ibuf[wv][jj];
                float v0 = hl[(size_t)ia.x * 64];
                float v1 = hl[(size_t)ia.y * 64];
                float v2 = hl[(size_t)ia.z * 64];
                float v3 = hl[(size_t)ia.w * 64];
                acc += (v0 + v1) + (v2 + v3);
            }
            for (; jj < m; ++jj) acc += hl[(size_t)ibuf[wv][jj] * 64];
        }
        xbuf[wv][lane] = acc;
        float outv = breg;
#pragma unroll
        for (int k4 = 0; k4 < 16; ++k4) {
            float4 xv = *(const float4*)&xbuf[wv][k4 * 4];
            outv = fmaf(xv.x, wcol[k4 * 4 + 0], outv);
            outv = fmaf(xv.y, wcol[k4 * 4 + 1], outv);
            outv = fmaf(xv.z, wcol[k4 * 4 + 2], outv);
            outv = fmaf(xv.w, wcol[k4 * 4 + 3], outv);
        }
        float h2v = fmaxf(outv, 0.f);
        float qv = h2v * whi;
        float rv = h2v * wlo;
#pragma unroll
        for (int off = 32; off >= 1; off >>= 1) {
            qv += __shfl_xor(qv, off, 64);
            rv += __shfl_xor(rv, off, 64);
        }
        if (lane == 0) {
            q[i] = qv;
            r[i] = rv;
        }
    }
}

// ============ pooling head ============

__global__ __launch_bounds__(256) void reduce_m2(const float* __restrict__ r,
                                                 float* __restrict__ m2, int N, int bpg) {
    int b = blockIdx.x / bpg, sub = blockIdx.x % bpg;
    const float* rb = r + (size_t)b * N;
    float a = 0.f;
    for (int n = sub * 256 + threadIdx.x; n < N; n += bpg * 256) a += rb[n];
    __shared__ float red[256];
    red[threadIdx.x] = a;
    __syncthreads();
    for (int off = 128; off >= 1; off >>= 1) {
        if (threadIdx.x < off) red[threadIdx.x] += red[threadIdx.x + off];
        __syncthreads();
    }
    if (threadIdx.x == 0) unsafeAtomicAdd(&m2[b], red[0]);
}

// wave per (graph, pathway): lanes read q[path[l]] directly (L2-resident)
__global__ __launch_bounds__(256) void pathway_score_wave(const float* __restrict__ q,
                                                          const int* __restrict__ pathway,
                                                          const float* __restrict__ m2,
                                                          const float* __restrict__ blin,
                                                          float* __restrict__ s,
                                                          int N, int P, int L, float invN,
                                                          int B) {
    int wid = (int)((blockIdx.x * blockDim.x + threadIdx.x) >> 6);
    int lane = threadIdx.x & 63;
    if (wid >= B * P) return;
    int b = wid / P, p = wid % P;
    const int* pw = pathway + (size_t)p * L;
    const float* qb = q + (size_t)b * N;
    float sum = 0.f;
    for (int l = lane; l < L; l += 64) sum += qb[pw[l]];
#pragma unroll
    for (int off = 32; off >= 1; off >>= 1) sum += __shfl_xor(sum, off, 64);
    if (lane == 0) s[wid] = tanhf(sum + m2[b] * invN + blin[0]);
}

__global__ __launch_bounds__(64) void out_softmax(const float* __restrict__ s,
                                                  const float* __restrict__ Wout,
                                                  const float* __restrict__ bout,
                                                  float* __restrict__ out, int B, int P) {
    __shared__ float logits[64];
    int tid = threadIdx.x;
    if (tid < B * 2) {
        int b = tid >> 1, k = tid & 1;
        float acc = bout[k];
        const float* sb = s + (size_t)b * P;
        for (int p = 0; p < P; ++p) acc = fmaf(sb[p], Wout[p * 2 + k], acc);
        logits[tid] = acc;
    }
    __syncthreads();
    if (tid < B) {
        float l0 = logits[tid * 2], l1 = logits[tid * 2 + 1];
        float m = fmaxf(l0, l1);
        float e0 = expf(l0 - m), e1 = expf(l1 - m);
        float inv = 1.f / (e0 + e1);
        out[tid * 2 + 0] = e0 * inv;
        out[tid * 2 + 1] = e1 * inv;
    }
}

extern "C" void kernel_launch(void* const* d_in, const int* in_sizes, int n_in,
                              void* d_out, int out_size, void* d_ws, size_t ws_size,
                              hipStream_t stream) {
    const float* h       = (const float*)d_in[0];
    const int*   src     = (const int*)d_in[1];
    const int*   dst     = (const int*)d_in[2];
    const int*   pathway = (const int*)d_in[3];
    const float* W1      = (const float*)d_in[5];
    const float* b1      = (const float*)d_in[6];
    const float* W2      = (const float*)d_in[7];
    const float* b2      = (const float*)d_in[8];
    const float* wlin    = (const float*)d_in[9];
    const float* blin    = (const float*)d_in[10];
    const float* Wout    = (const float*)d_in[11];
    const float* bout    = (const float*)d_in[12];
    float*       out     = (float*)d_out;

    const int BN = in_sizes[0] / 16;
    const int E  = in_sizes[1];
    const int P  = in_sizes[11] / 2;
    const int L  = in_sizes[3] / P;
    const int B  = out_size / 2;
    const int N  = BN / B;
    const int nb = (BN + 1023) / 1024;

    char* ws = (char*)d_ws;
    size_t o = 0;
    float* tmp0    = (float*)(ws + o); o += align256((size_t)BN * 16 * 4);
    float* h1      = (float*)(ws + o); o += align256((size_t)BN * 64 * 4);
    float* qbuf    = (float*)(ws + o); o += align256((size_t)BN * 4);
    float* rbuf    = (float*)(ws + o); o += align256((size_t)BN * 4);
    float* m2      = (float*)(ws + o); o += align256((size_t)B * 4);
    float* sbuf    = (float*)(ws + o); o += align256((size_t)B * P * 4);
    int*   counts8 = (int*)(ws + o);   o += align256((size_t)BN * 8 * 4);
    int*   totals  = (int*)(ws + o);   o += align256((size_t)BN * 4);
    int*   offs    = (int*)(ws + o);   o += align256((size_t)BN * 4);
    int*   rank    = (int*)(ws + o);   o += align256((size_t)E * 4);
    int*   esrc    = (int*)(ws + o);   o += align256((size_t)E * 4);
    int*   bsum    = (int*)(ws + o);   o += align256((size_t)nb * 4);
    int*   bpre    = (int*)(ws + o);   o += align256((size_t)nb * 4);
    (void)ws_size; (void)n_in;

    // ---- build CSR (dst -> list of src), atomics only on XCD-local replicas ----
    hipMemsetAsync(counts8, 0, (size_t)BN * 8 * 4, stream);
    hipMemsetAsync(m2, 0, (size_t)B * 4, stream);
    csr_count_rank8<<<(E + 255) / 256, 256, 0, stream>>>(dst, counts8, rank, E, BN);
    merge_counts<<<(BN + 255) / 256, 256, 0, stream>>>(counts8, totals, BN);
    block_reduce<<<nb, 256, 0, stream>>>(totals, bsum, BN);
    scan_small<<<1, 1024, 0, stream>>>(bsum, bpre, nb);
    block_scan<<<nb, 256, 0, stream>>>(totals, bpre, offs, BN);
    csr_fill3<<<(E + 255) / 256, 256, 0, stream>>>(src, dst, rank, offs, counts8, esrc, E, BN);

    // ---- layer 1 ----
    gather16<<<(BN * 4 + 255) / 256, 256, 0, stream>>>((const float4*)h, offs, totals, esrc,
                                                       (float4*)tmp0, BN);
    lin1_wave<<<2048, 256, 0, stream>>>(tmp0, W1, b1, h1, BN);

    // ---- fused layer 2 + projection (h2 never materialized) ----
    gather64_lin2_qr<<<2048, 256, 0, stream>>>(h1, offs, totals, esrc, W2, b2, wlin,
                                               qbuf, rbuf, BN);

    // ---- pooling head ----
    reduce_m2<<<B * 8, 256, 0, stream>>>(rbuf, m2, N, 8);
    pathway_score_wave<<<(B * P + 3) / 4, 256, 0, stream>>>(qbuf, pathway, m2, blin, sbuf,
                                                            N, P, L, 1.0f / (float)N, B);
    out_softmax<<<1, 64, 0, stream>>>(sbuf, Wout, bout, out, B, P);
}

// Round 7
// 372.081 us; speedup vs baseline: 1.0706x; 1.0706x over previous
//
#include <hip/hip_runtime.h>
#include <math.h>

static inline size_t align256(size_t x) { return (x + 255) & ~size_t(255); }

// ============ CSR construction (dst-range sharded: shard s <-> XCD s) ============

// Each shard's blocks scan ALL edges, act only on dst in [lo,hi).
// Counters for shard s live in an XCD-local L2 region -> no cross-XCD atomic ping-pong.
__global__ __launch_bounds__(256) void csr_count_shard(const int* __restrict__ dst,
                                                       int* __restrict__ counts,
                                                       int* __restrict__ rank, int E, int BN) {
    int s  = blockIdx.x & 7;
    int bs = blockIdx.x >> 3;
    int nb = gridDim.x >> 3;
    int lo = (int)(((long long)BN * s) >> 3);
    int hi = (int)(((long long)BN * (s + 1)) >> 3);
    for (int e = bs * 256 + threadIdx.x; e < E; e += nb * 256) {
        int d = dst[e];
        if (d >= lo && d < hi) rank[e] = atomicAdd(&counts[d], 1);
    }
}

__global__ __launch_bounds__(256) void block_reduce(const int* __restrict__ counts,
                                                    int* __restrict__ bsum, int BN) {
    __shared__ int red[256];
    int base = blockIdx.x * 1024;
    int s = 0;
    for (int k = threadIdx.x; k < 1024; k += 256) {
        int idx = base + k;
        s += (idx < BN) ? counts[idx] : 0;
    }
    red[threadIdx.x] = s;
    __syncthreads();
    for (int off = 128; off >= 1; off >>= 1) {
        if (threadIdx.x < off) red[threadIdx.x] += red[threadIdx.x + off];
        __syncthreads();
    }
    if (threadIdx.x == 0) bsum[blockIdx.x] = red[0];
}

__global__ __launch_bounds__(1024) void scan_small(const int* __restrict__ bsum,
                                                   int* __restrict__ bpre, int nb) {
    __shared__ int buf[1024];
    int tid = threadIdx.x;
    buf[tid] = (tid < nb) ? bsum[tid] : 0;
    __syncthreads();
    for (int off = 1; off < 1024; off <<= 1) {
        int v = (tid >= off) ? buf[tid - off] : 0;
        __syncthreads();
        buf[tid] += v;
        __syncthreads();
    }
    if (tid < nb) bpre[tid] = (tid == 0) ? 0 : buf[tid - 1];
}

__global__ __launch_bounds__(256) void block_scan(const int* __restrict__ counts,
                                                  const int* __restrict__ bpre,
                                                  int* __restrict__ offs, int BN) {
    __shared__ int tsum[256];
    int base = blockIdx.x * 1024;
    int tbase = base + threadIdx.x * 4;
    int c0 = 0, c1 = 0, c2 = 0, c3 = 0;
    if (tbase + 0 < BN) c0 = counts[tbase + 0];
    if (tbase + 1 < BN) c1 = counts[tbase + 1];
    if (tbase + 2 < BN) c2 = counts[tbase + 2];
    if (tbase + 3 < BN) c3 = counts[tbase + 3];
    int local = c0 + c1 + c2 + c3;
    tsum[threadIdx.x] = local;
    __syncthreads();
    for (int off = 1; off < 256; off <<= 1) {
        int v = (threadIdx.x >= off) ? tsum[threadIdx.x - off] : 0;
        __syncthreads();
        tsum[threadIdx.x] += v;
        __syncthreads();
    }
    int prefix = bpre[blockIdx.x] + tsum[threadIdx.x] - local;  // exclusive
    if (tbase + 0 < BN) offs[tbase + 0] = prefix;
    prefix += c0;
    if (tbase + 1 < BN) offs[tbase + 1] = prefix;
    prefix += c1;
    if (tbase + 2 < BN) offs[tbase + 2] = prefix;
    prefix += c2;
    if (tbase + 3 < BN) offs[tbase + 3] = prefix;
}

// Sharded fill: esrc region for shard s is written only by XCD s (no atomics).
__global__ __launch_bounds__(256) void csr_fill_shard(const int* __restrict__ src,
                                                      const int* __restrict__ dst,
                                                      const int* __restrict__ rank,
                                                      const int* __restrict__ offs,
                                                      int* __restrict__ esrc, int E, int BN) {
    int s  = blockIdx.x & 7;
    int bs = blockIdx.x >> 3;
    int nb = gridDim.x >> 3;
    int lo = (int)(((long long)BN * s) >> 3);
    int hi = (int)(((long long)BN * (s + 1)) >> 3);
    for (int e = bs * 256 + threadIdx.x; e < E; e += nb * 256) {
        int d = dst[e];
        if (d >= lo && d < hi) esrc[offs[d] + rank[e]] = src[e];
    }
}

// ============ fused layer 1: gather16 + lin1 + relu ============
// wave per node. lane = 16*group + feat; 4 neighbor rows processed in parallel.
__global__ __launch_bounds__(256) void gin1_fused(const float* __restrict__ h,
                                                  const int* __restrict__ offs,
                                                  const int* __restrict__ cnts,
                                                  const int* __restrict__ esrc,
                                                  const float* __restrict__ W1,
                                                  const float* __restrict__ b1,
                                                  float* __restrict__ h1, int BN) {
    __shared__ float xb[4][16];
    __shared__ int   ibuf[4][64];
    int tid = threadIdx.x;
    int lane = tid & 63, wv = tid >> 6;
    int fg = lane >> 4, ft = lane & 15;
    int gw = (int)((blockIdx.x * blockDim.x + tid) >> 6);
    int nw = (int)((gridDim.x * blockDim.x) >> 6);
    float wcol[16];
#pragma unroll
    for (int k = 0; k < 16; ++k) wcol[k] = W1[k * 64 + lane];
    float breg = b1[lane];
    for (int i = gw; i < BN; i += nw) {
        float acc = (fg == 0) ? h[(size_t)i * 16 + ft] : 0.f;
        int start = offs[i], deg = cnts[i];
        for (int j0 = 0; j0 < deg; j0 += 64) {
            int m = min(64, deg - j0);
            if (lane < m) ibuf[wv][lane] = esrc[start + j0 + lane];
            int jj = fg;
            for (; jj + 4 < m; jj += 8) {
                int s0 = ibuf[wv][jj];
                int s1 = ibuf[wv][jj + 4];
                acc += h[(size_t)s0 * 16 + ft] + h[(size_t)s1 * 16 + ft];
            }
            if (jj < m) acc += h[(size_t)ibuf[wv][jj] * 16 + ft];
        }
        // combine the 4 neighbor-groups: every lane ends with total for feature ft
        acc += __shfl_xor(acc, 16, 64);
        acc += __shfl_xor(acc, 32, 64);
        if (lane < 16) xb[wv][lane] = acc;
        float o = breg;
#pragma unroll
        for (int k4 = 0; k4 < 4; ++k4) {
            float4 xv = *(const float4*)&xb[wv][k4 * 4];
            o = fmaf(xv.x, wcol[k4 * 4 + 0], o);
            o = fmaf(xv.y, wcol[k4 * 4 + 1], o);
            o = fmaf(xv.z, wcol[k4 * 4 + 2], o);
            o = fmaf(xv.w, wcol[k4 * 4 + 3], o);
        }
        h1[(size_t)i * 64 + lane] = fmaxf(o, 0.f);
    }
}

// ============ fused layer 2: gather + lin2 + relu + project to (q, r) ============
__global__ __launch_bounds__(256, 4) void gather64_lin2_qr(const float* __restrict__ h1,
                                                           const int* __restrict__ offs,
                                                           const int* __restrict__ cnts,
                                                           const int* __restrict__ esrc,
                                                           const float* __restrict__ W2,
                                                           const float* __restrict__ b2,
                                                           const float* __restrict__ wlin,
                                                           float* __restrict__ q,
                                                           float* __restrict__ r, int BN) {
    __shared__ float xbuf[4][64];
    __shared__ int   ibuf[4][64];
    int tid = threadIdx.x;
    int lane = tid & 63, wv = tid >> 6;
    int gw = (int)((blockIdx.x * blockDim.x + tid) >> 6);
    int nw = (int)((gridDim.x * blockDim.x) >> 6);
    float wcol[64];
#pragma unroll
    for (int k = 0; k < 64; ++k) wcol[k] = W2[k * 64 + lane];
    float breg = b2[lane];
    float wlo = wlin[lane];
    float whi = wlin[64 + lane];
    const float* hl = h1 + lane;
    for (int i = gw; i < BN; i += nw) {
        float acc = hl[(size_t)i * 64];
        int start = offs[i], deg = cnts[i];
        for (int j0 = 0; j0 < deg; j0 += 64) {
            int m = min(64, deg - j0);
            if (lane < m) ibuf[wv][lane] = esrc[start + j0 + lane];
            int jj = 0;
            for (; jj + 8 <= m; jj += 8) {
                int4 ia = *(const int4*)&ibuf[wv][jj];
                int4 ib = *(const int4*)&ibuf[wv][jj + 4];
                float v0 = hl[(size_t)ia.x * 64];
                float v1 = hl[(size_t)ia.y * 64];
                float v2 = hl[(size_t)ia.z * 64];
                float v3 = hl[(size_t)ia.w * 64];
                float v4 = hl[(size_t)ib.x * 64];
                float v5 = hl[(size_t)ib.y * 64];
                float v6 = hl[(size_t)ib.z * 64];
                float v7 = hl[(size_t)ib.w * 64];
                acc += ((v0 + v1) + (v2 + v3)) + ((v4 + v5) + (v6 + v7));
            }
            for (; jj + 4 <= m; jj += 4) {
                int4 ia = *(const int4*)&ibuf[wv][jj];
                float v0 = hl[(size_t)ia.x * 64];
                float v1 = hl[(size_t)ia.y * 64];
                float v2 = hl[(size_t)ia.z * 64];
                float v3 = hl[(size_t)ia.w * 64];
                acc += (v0 + v1) + (v2 + v3);
            }
            for (; jj < m; ++jj) acc += hl[(size_t)ibuf[wv][jj] * 64];
        }
        xbuf[wv][lane] = acc;
        float outv = breg;
#pragma unroll
        for (int k4 = 0; k4 < 16; ++k4) {
            float4 xv = *(const float4*)&xbuf[wv][k4 * 4];
            outv = fmaf(xv.x, wcol[k4 * 4 + 0], outv);
            outv = fmaf(xv.y, wcol[k4 * 4 + 1], outv);
            outv = fmaf(xv.z, wcol[k4 * 4 + 2], outv);
            outv = fmaf(xv.w, wcol[k4 * 4 + 3], outv);
        }
        float h2v = fmaxf(outv, 0.f);
        float qv = h2v * whi;
        float rv = h2v * wlo;
#pragma unroll
        for (int off = 32; off >= 1; off >>= 1) {
            qv += __shfl_xor(qv, off, 64);
            rv += __shfl_xor(rv, off, 64);
        }
        if (lane == 0) {
            q[i] = qv;
            r[i] = rv;
        }
    }
}

// ============ pooling head ============

__global__ __launch_bounds__(256) void reduce_m2(const float* __restrict__ r,
                                                 float* __restrict__ m2, int N, int bpg) {
    int b = blockIdx.x / bpg, sub = blockIdx.x % bpg;
    const float* rb = r + (size_t)b * N;
    float a = 0.f;
    for (int n = sub * 256 + threadIdx.x; n < N; n += bpg * 256) a += rb[n];
    __shared__ float red[256];
    red[threadIdx.x] = a;
    __syncthreads();
    for (int off = 128; off >= 1; off >>= 1) {
        if (threadIdx.x < off) red[threadIdx.x] += red[threadIdx.x + off];
        __syncthreads();
    }
    if (threadIdx.x == 0) unsafeAtomicAdd(&m2[b], red[0]);
}

__global__ __launch_bounds__(256) void pathway_score_wave(const float* __restrict__ q,
                                                          const int* __restrict__ pathway,
                                                          const float* __restrict__ m2,
                                                          const float* __restrict__ blin,
                                                          float* __restrict__ s,
                                                          int N, int P, int L, float invN,
                                                          int B) {
    int wid = (int)((blockIdx.x * blockDim.x + threadIdx.x) >> 6);
    int lane = threadIdx.x & 63;
    if (wid >= B * P) return;
    int b = wid / P, p = wid % P;
    const int* pw = pathway + (size_t)p * L;
    const float* qb = q + (size_t)b * N;
    float sum = 0.f;
    for (int l = lane; l < L; l += 64) sum += qb[pw[l]];
#pragma unroll
    for (int off = 32; off >= 1; off >>= 1) sum += __shfl_xor(sum, off, 64);
    if (lane == 0) s[wid] = tanhf(sum + m2[b] * invN + blin[0]);
}

// wave per graph
__global__ __launch_bounds__(64) void out_softmax_wave(const float* __restrict__ s,
                                                       const float* __restrict__ Wout,
                                                       const float* __restrict__ bout,
                                                       float* __restrict__ out, int P) {
    int b = blockIdx.x;
    int lane = threadIdx.x;
    const float* sb = s + (size_t)b * P;
    float a0 = 0.f, a1 = 0.f;
    for (int p = lane; p < P; p += 64) {
        float sv = sb[p];
        a0 = fmaf(sv, Wout[p * 2 + 0], a0);
        a1 = fmaf(sv, Wout[p * 2 + 1], a1);
    }
#pragma unroll
    for (int off = 32; off >= 1; off >>= 1) {
        a0 += __shfl_xor(a0, off, 64);
        a1 += __shfl_xor(a1, off, 64);
    }
    if (lane == 0) {
        float l0 = a0 + bout[0], l1 = a1 + bout[1];
        float m = fmaxf(l0, l1);
        float e0 = expf(l0 - m), e1 = expf(l1 - m);
        float inv = 1.f / (e0 + e1);
        out[b * 2 + 0] = e0 * inv;
        out[b * 2 + 1] = e1 * inv;
    }
}

extern "C" void kernel_launch(void* const* d_in, const int* in_sizes, int n_in,
                              void* d_out, int out_size, void* d_ws, size_t ws_size,
                              hipStream_t stream) {
    const float* h       = (const float*)d_in[0];
    const int*   src     = (const int*)d_in[1];
    const int*   dst     = (const int*)d_in[2];
    const int*   pathway = (const int*)d_in[3];
    const float* W1      = (const float*)d_in[5];
    const float* b1      = (const float*)d_in[6];
    const float* W2      = (const float*)d_in[7];
    const float* b2      = (const float*)d_in[8];
    const float* wlin    = (const float*)d_in[9];
    const float* blin    = (const float*)d_in[10];
    const float* Wout    = (const float*)d_in[11];
    const float* bout    = (const float*)d_in[12];
    float*       out     = (float*)d_out;

    const int BN = in_sizes[0] / 16;
    const int E  = in_sizes[1];
    const int P  = in_sizes[11] / 2;
    const int L  = in_sizes[3] / P;
    const int B  = out_size / 2;
    const int N  = BN / B;
    const int nb = (BN + 1023) / 1024;

    char* ws = (char*)d_ws;
    size_t o = 0;
    float* h1     = (float*)(ws + o); o += align256((size_t)BN * 64 * 4);
    float* qbuf   = (float*)(ws + o); o += align256((size_t)BN * 4);
    float* rbuf   = (float*)(ws + o); o += align256((size_t)BN * 4);
    float* m2     = (float*)(ws + o); o += align256((size_t)B * 4);
    float* sbuf   = (float*)(ws + o); o += align256((size_t)B * P * 4);
    int*   counts = (int*)(ws + o);   o += align256((size_t)BN * 4);
    int*   offs   = (int*)(ws + o);   o += align256((size_t)BN * 4);
    int*   rank   = (int*)(ws + o);   o += align256((size_t)E * 4);
    int*   esrc   = (int*)(ws + o);   o += align256((size_t)E * 4);
    int*   bsum   = (int*)(ws + o);   o += align256((size_t)nb * 4);
    int*   bpre   = (int*)(ws + o);   o += align256((size_t)nb * 4);
    (void)ws_size; (void)n_in;

    // ---- build CSR (dst -> list of src), XCD-sharded atomics & stores ----
    hipMemsetAsync(counts, 0, (size_t)BN * 4, stream);
    hipMemsetAsync(m2, 0, (size_t)B * 4, stream);
    csr_count_shard<<<2048, 256, 0, stream>>>(dst, counts, rank, E, BN);
    block_reduce<<<nb, 256, 0, stream>>>(counts, bsum, BN);
    scan_small<<<1, 1024, 0, stream>>>(bsum, bpre, nb);
    block_scan<<<nb, 256, 0, stream>>>(counts, bpre, offs, BN);
    csr_fill_shard<<<2048, 256, 0, stream>>>(src, dst, rank, offs, esrc, E, BN);

    // ---- fused layer 1 (gather16 + lin1 + relu) ----
    gin1_fused<<<2048, 256, 0, stream>>>(h, offs, counts, esrc, W1, b1, h1, BN);

    // ---- fused layer 2 + projection (h2 never materialized) ----
    gather64_lin2_qr<<<2048, 256, 0, stream>>>(h1, offs, counts, esrc, W2, b2, wlin,
                                               qbuf, rbuf, BN);

    // ---- pooling head ----
    reduce_m2<<<B * 8, 256, 0, stream>>>(rbuf, m2, N, 8);
    pathway_score_wave<<<(B * P + 3) / 4, 256, 0, stream>>>(qbuf, pathway, m2, blin, sbuf,
                                                            N, P, L, 1.0f / (float)N, B);
    out_softmax_wave<<<B, 64, 0, stream>>>(sbuf, Wout, bout, out, P);
}